// Round 4
// baseline (121.945 us; speedup 1.0000x reference)
//
#include <hip/hip_runtime.h>

// Problem constants (match reference)
constexpr int BB = 256;
constexpr int SS = 8192;
constexpr int NPOS = BB * SS;           // 2,097,152 positions
constexpr int IGNORE = -100;
constexpr int GRID = 1024;              // blocks; each thread: 2 chunks x 4 pos
constexpr int NCHUNK = 2;               // NPOS / (GRID*256*4)
// GAMMA = 2.0 -> (1-pt)^2

// focal CE, short dependency chain (validated absmax 0.0 in R1-R3):
//   ce = log(s) + (m - x);  pt = e_lab * rcp(s)  (rcp runs parallel to log)
__device__ __forceinline__ void focal_acc(float l0, float l1, float l2,
                                          int lab, float& fl, float& cnt) {
    if (lab == IGNORE) return;
    float m  = fmaxf(l0, fmaxf(l1, l2));
    float e0 = __expf(l0 - m), e1 = __expf(l1 - m), e2 = __expf(l2 - m);
    float s  = e0 + e1 + e2;
    float x  = (lab == 0) ? l0 : ((lab == 1) ? l1 : l2);
    float el = (lab == 0) ? e0 : ((lab == 1) ? e1 : e2);
    float ce = __logf(s) + (m - x);
    float pt = el * __builtin_amdgcn_rcpf(s);   // == exp(-ce)
    float om = 1.0f - pt;
    fl  += om * om * ce;
    cnt += 1.0f;
}

__device__ __forceinline__ float bce_term(float z, float y) {
    // max(z,0) - z*y + log1p(exp(-|z|))
    return fmaxf(z, 0.0f) - z * y + __logf(1.0f + __expf(-fabsf(z)));
}

// ws layout: float partial[5][GRID]  (5 * 1024 * 4B = 20 KB)
__global__ __launch_bounds__(256)
void main_kernel(const float* __restrict__ a_logits,
                 const float* __restrict__ o_logits,
                 const float* __restrict__ b_logits,
                 const int*   __restrict__ a_labels,
                 const int*   __restrict__ o_labels,
                 float*       __restrict__ partial) {
    int lane = threadIdx.x & 63;
    float fl_a = 0.f, cnt_a = 0.f, fl_o = 0.f, cnt_o = 0.f, bce = 0.f;

    // per-chunk first position: chunk c covers segment (blockIdx + c*GRID)
    int p[NCHUNK];
    #pragma unroll
    for (int c = 0; c < NCHUNK; ++c)
        p[c] = (blockIdx.x + c * GRID) * 1024 + threadIdx.x * 4;

    // ---- issue ALL loads for BOTH chunks up front (20 VMEM in flight) ----
    int4   al4[NCHUNK], ol4[NCHUNK];
    float4 A0[NCHUNK], A1[NCHUNK], A2[NCHUNK];
    float4 O0[NCHUNK], O1[NCHUNK], O2[NCHUNK];
    float4 Z0[NCHUNK], Z1[NCHUNK];
    #pragma unroll
    for (int c = 0; c < NCHUNK; ++c) {
        int p0 = p[c];
        al4[c] = *(const int4*)(a_labels + p0);
        ol4[c] = *(const int4*)(o_labels + p0);
        const float4* ap = (const float4*)(a_logits + p0 * 3);
        const float4* op = (const float4*)(o_logits + p0 * 3);
        const float4* bp = (const float4*)(b_logits + p0 * 2);
        A0[c] = ap[0]; A1[c] = ap[1]; A2[c] = ap[2];
        O0[c] = op[0]; O1[c] = op[1]; O2[c] = op[2];
        Z0[c] = bp[0]; Z1[c] = bp[1];
    }

    #pragma unroll
    for (int c = 0; c < NCHUNK; ++c) {
        int p0 = p[c];
        // next-label for position p0+3: lane+1's al4.x (waves cover 256
        // consecutive positions; row end (multiple of 8192) only falls on
        // lane 63's last position)
        int al_next = __shfl_down(al4[c].x, 1, 64);
        int ol_next = __shfl_down(ol4[c].x, 1, 64);
        if (lane == 63) {
            if (((p0 + 3) & (SS - 1)) != SS - 1) {
                al_next = a_labels[p0 + 4];
                ol_next = o_labels[p0 + 4];
            } else {
                al_next = -1;            // JAX concat(..., -1) sentinel
                ol_next = -1;
            }
        }
        int al[5] = {al4[c].x, al4[c].y, al4[c].z, al4[c].w, al_next};
        int ol[5] = {ol4[c].x, ol4[c].y, ol4[c].z, ol4[c].w, ol_next};

        float aL[12] = {A0[c].x, A0[c].y, A0[c].z, A0[c].w,
                        A1[c].x, A1[c].y, A1[c].z, A1[c].w,
                        A2[c].x, A2[c].y, A2[c].z, A2[c].w};
        float oL[12] = {O0[c].x, O0[c].y, O0[c].z, O0[c].w,
                        O1[c].x, O1[c].y, O1[c].z, O1[c].w,
                        O2[c].x, O2[c].y, O2[c].z, O2[c].w};
        float z[8]   = {Z0[c].x, Z0[c].y, Z0[c].z, Z0[c].w,
                        Z1[c].x, Z1[c].y, Z1[c].z, Z1[c].w};

        #pragma unroll
        for (int j = 0; j < 4; ++j) {
            focal_acc(aL[3*j], aL[3*j+1], aL[3*j+2], al[j], fl_a, cnt_a);
            focal_acc(oL[3*j], oL[3*j+1], oL[3*j+2], ol[j], fl_o, cnt_o);
            float ys = ((al[j] == 1) || (ol[j] == 1)) ? 1.0f : 0.0f;
            float ye = (((al[j] == 2) && (al[j+1] != 2)) ||
                        ((ol[j] == 2) && (ol[j+1] != 2))) ? 1.0f : 0.0f;
            bce += bce_term(z[2*j],     ys);
            bce += bce_term(z[2*j + 1], ye);
        }
    }

    // block reduction: wave64 shuffle -> LDS -> thread0 writes block partial
    float vals[5] = {fl_a, cnt_a, fl_o, cnt_o, bce};
    #pragma unroll
    for (int k = 0; k < 5; ++k) {
        float v = vals[k];
        #pragma unroll
        for (int o = 32; o > 0; o >>= 1) v += __shfl_down(v, o, 64);
        vals[k] = v;
    }
    __shared__ float lds[4 * 5];
    int wid = threadIdx.x >> 6;
    if (lane == 0) {
        #pragma unroll
        for (int k = 0; k < 5; ++k) lds[wid * 5 + k] = vals[k];
    }
    __syncthreads();
    if (threadIdx.x == 0) {
        #pragma unroll
        for (int k = 0; k < 5; ++k) {
            float s = lds[k] + lds[5 + k] + lds[10 + k] + lds[15 + k];
            partial[k * GRID + blockIdx.x] = s;   // plane layout, no atomics
        }
    }
}

__global__ __launch_bounds__(256)
void sent_final_kernel(const float* __restrict__ s_logits,
                       const int*   __restrict__ s_labels,
                       const float* __restrict__ partial,
                       float* __restrict__ out) {
    int tid = threadIdx.x;               // 256 threads

    // --- reduce the 5 partial planes (1024 each, coalesced, 4 rounds) ---
    float acc[5];
    #pragma unroll
    for (int k = 0; k < 5; ++k) {
        float s = 0.f;
        #pragma unroll
        for (int i = 0; i < GRID / 256; ++i)       // 4 iters
            s += partial[k * GRID + tid + i * 256];
        acc[k] = s;
    }

    // --- sentiment CE (one element per thread, B=256) ---
    float ce = 0.f, cnt = 0.f;
    {
        int lab = s_labels[tid];
        if (lab != IGNORE) {
            float l0 = s_logits[3*tid], l1 = s_logits[3*tid+1], l2 = s_logits[3*tid+2];
            float m   = fmaxf(l0, fmaxf(l1, l2));
            float lse = m + __logf(__expf(l0-m) + __expf(l1-m) + __expf(l2-m));
            float x   = (lab == 0) ? l0 : ((lab == 1) ? l1 : l2);
            ce  = lse - x;
            cnt = 1.0f;
        }
    }

    float vals[7] = {acc[0], acc[1], acc[2], acc[3], acc[4], ce, cnt};
    #pragma unroll
    for (int k = 0; k < 7; ++k) {
        float v = vals[k];
        #pragma unroll
        for (int o = 32; o > 0; o >>= 1) v += __shfl_down(v, o, 64);
        vals[k] = v;
    }
    __shared__ float lds[4 * 7];
    int lane = threadIdx.x & 63, wid = threadIdx.x >> 6;
    if (lane == 0) {
        #pragma unroll
        for (int k = 0; k < 7; ++k) lds[wid * 7 + k] = vals[k];
    }
    __syncthreads();
    if (threadIdx.x == 0) {
        float tot[7];
        #pragma unroll
        for (int k = 0; k < 7; ++k)
            tot[k] = lds[k] + lds[7 + k] + lds[14 + k] + lds[21 + k];
        double fl_a = tot[0], ca = tot[1], fl_o = tot[2], co = tot[3];
        double bsum = tot[4], sv = tot[5], sc = tot[6];
        double aspect  = (ca > 0.0) ? fl_a / fmax(ca, 1.0) : 0.0;
        double opinion = (co > 0.0) ? fl_o / fmax(co, 1.0) : 0.0;
        double senti   = sv / fmax(sc, 1.0);
        double bnd     = bsum / (double)((long long)NPOS * 2);
        out[0] = (float)(aspect + opinion + senti + 0.5 * bnd);
    }
}

extern "C" void kernel_launch(void* const* d_in, const int* in_sizes, int n_in,
                              void* d_out, int out_size, void* d_ws, size_t ws_size,
                              hipStream_t stream) {
    const float* a_logits = (const float*)d_in[0];   // (B,S,3)
    const float* o_logits = (const float*)d_in[1];   // (B,S,3)
    const float* s_logits = (const float*)d_in[2];   // (B,3)
    const float* b_logits = (const float*)d_in[3];   // (B,S,2)
    const int*   a_labels = (const int*)d_in[4];     // (B,S)
    const int*   o_labels = (const int*)d_in[5];     // (B,S)
    const int*   s_labels = (const int*)d_in[6];     // (B,)
    float* out = (float*)d_out;
    float* partial = (float*)d_ws;                   // 5 * 1024 floats = 20 KB

    main_kernel<<<GRID, 256, 0, stream>>>(a_logits, o_logits, b_logits,
                                          a_labels, o_labels, partial);
    sent_final_kernel<<<1, 256, 0, stream>>>(s_logits, s_labels, partial, out);
}